// Round 18
// baseline (2059.070 us; speedup 1.0000x reference)
//
#include <hip/hip_runtime.h>
#include <math.h>

constexpr int B = 2;
constexpr int F = 2112;
constexpr int D = 1024;
constexpr int H = 8;
constexpr int DH = 64;
constexpr int INNER = H * DH;      // 512
constexpr int NL = 721;
constexpr int NL_PAD = 768;
constexpr int MLAT = B * NL;       // 1442
constexpr int MLAT_PAD = 1536;
constexpr int VD = 64;
constexpr int DEPTH = 6;
constexpr int FN = F + NL;         // 2833
constexpr int FN_PAD = 2880;       // 45 * 64
constexpr int NBH = B * H;         // 16
constexpr int SKVMAX = 8;
constexpr int MX = B * F;          // 4224
constexpr int NBIAS = 6656;        // 512(q) + 1024(kv-lat) + 1024(kv-x) + 4096(ffn)
constexpr int NT_FFW2 = 23 * 16 * 8;   // 2944
constexpr int NT_KVX  = 66 * 16;       // 1056
constexpr float EPS = 1e-5f;

typedef __bf16 bf16x8 __attribute__((ext_vector_type(8)));
typedef float  f32x4  __attribute__((ext_vector_type(4)));

static __device__ __forceinline__ unsigned short f2bf(float f)
{
    union { float f; unsigned int u; } x; x.f = f;
    unsigned int r = x.u + 0x7FFFu + ((x.u >> 16) & 1u);   // RNE
    return (unsigned short)(r >> 16);
}
static __device__ __forceinline__ float bf2f(unsigned short u)
{
    union { unsigned int i; float f; } x; x.i = ((unsigned int)u) << 16; return x.f;
}

// XCD-chunked bijective block->tile mapping. Requires nt % 8 == 0.
static __device__ __forceinline__ int xcd_swz(int b, int nt)
{
    return (b & 7) * (nt >> 3) + (b >> 3);
}

// ---------------- block reduce (sum, sumsq) over 256 threads ----------------
__device__ __forceinline__ void block_reduce_2(float& s, float& ss, float* red)
{
#pragma unroll
    for (int off = 32; off; off >>= 1) {
        s  += __shfl_xor(s, off);
        ss += __shfl_xor(ss, off);
    }
    int wv = threadIdx.x >> 6;
    if ((threadIdx.x & 63) == 0) { red[wv] = s; red[4 + wv] = ss; }
    __syncthreads();
    s  = red[0] + red[1] + red[2] + red[3];
    ss = red[4] + red[5] + red[6] + red[7];
}

// ------- x + spatial_emb + frame_emb, then row-normalize -> bf16 xhat -------
__global__ __launch_bounds__(256) void emb_ln_kernel(
    const float* __restrict__ x, const float* __restrict__ sp_emb,
    const float* __restrict__ fr_emb, unsigned short* __restrict__ xhat)
{
    __shared__ float red[8];
    int r = blockIdx.x;            // r = b*F + j
    int j = r % F;
    int t = threadIdx.x;
    const float4* xr = (const float4*)(x + (long)r * D);
    int spr = (j < VD) ? j : VD;
    int frr = (j < VD) ? 0 : (j - VD + 1);
    const float4* sp4 = (const float4*)(sp_emb + (long)spr * D);
    const float4* fr4 = (const float4*)(fr_emb + (long)frr * D);
    float4 v = xr[t], a = sp4[t], c = fr4[t];
    v.x += a.x + c.x; v.y += a.y + c.y; v.z += a.z + c.z; v.w += a.w + c.w;
    float s  = v.x + v.y + v.z + v.w;
    float ss = v.x*v.x + v.y*v.y + v.z*v.z + v.w*v.w;
    block_reduce_2(s, ss, red);
    float mean = s * (1.0f / D);
    float var  = ss * (1.0f / D) - mean * mean;
    float rstd = rsqrtf(var + EPS);
    ushort4 o;
    o.x = f2bf((v.x - mean) * rstd);
    o.y = f2bf((v.y - mean) * rstd);
    o.z = f2bf((v.z - mean) * rstd);
    o.w = f2bf((v.w - mean) * rstd);
    ((ushort4*)(xhat + (long)r * D))[t] = o;
}

// --------------------- plain row-normalize -> bf16 ---------------------------
__global__ __launch_bounds__(256) void rownorm_plain_kernel(
    const float* __restrict__ in, unsigned short* __restrict__ out)
{
    __shared__ float red[8];
    int r = blockIdx.x;
    int t = threadIdx.x;
    float4 v = ((const float4*)(in + (long)r * D))[t];
    float s  = v.x + v.y + v.z + v.w;
    float ss = v.x*v.x + v.y*v.y + v.z*v.z + v.w*v.w;
    block_reduce_2(s, ss, red);
    float mean = s * (1.0f / D);
    float var  = ss * (1.0f / D) - mean * mean;
    float rstd = rsqrtf(var + EPS);
    ushort4 o;
    o.x = f2bf((v.x - mean) * rstd);
    o.y = f2bf((v.y - mean) * rstd);
    o.z = f2bf((v.z - mean) * rstd);
    o.w = f2bf((v.w - mean) * rstd);
    ((ushort4*)(out + (long)r * D))[t] = o;
}

// ------------------------ final LN with affine -> out ------------------------
__global__ __launch_bounds__(256) void final_ln_kernel(
    const float* __restrict__ in, const float* __restrict__ g,
    const float* __restrict__ b, float* __restrict__ out)
{
    __shared__ float red[8];
    int r = blockIdx.x;
    int t = threadIdx.x;
    float4 v = ((const float4*)(in + (long)r * D))[t];
    float s  = v.x + v.y + v.z + v.w;
    float ss = v.x*v.x + v.y*v.y + v.z*v.z + v.w*v.w;
    block_reduce_2(s, ss, red);
    float mean = s * (1.0f / D);
    float var  = ss * (1.0f / D) - mean * mean;
    float rstd = rsqrtf(var + EPS);
    float4 g4 = ((const float4*)g)[t];
    float4 b4 = ((const float4*)b)[t];
    float4 o;
    o.x = (v.x - mean) * rstd * g4.x + b4.x;
    o.y = (v.y - mean) * rstd * g4.y + b4.y;
    o.z = (v.z - mean) * rstd * g4.z + b4.z;
    o.w = (v.w - mean) * rstd * g4.w + b4.w;
    ((float4*)(out + (long)r * D))[t] = o;
}

// ---------------------- lat init: broadcast latents to B ---------------------
__global__ __launch_bounds__(256) void lat_init_kernel(
    const float* __restrict__ latents, float* __restrict__ lat)
{
    int r = blockIdx.x;            // b*NL + i
    int i = r % NL;
    int t = threadIdx.x;
    ((float4*)(lat + (long)r * D))[t] = ((const float4*)(latents + (long)i * D))[t];
}

// ------------- bias rows: bias[l][o] += b_slice @ W column o -----------------
__global__ __launch_bounds__(256) void bias_kernel(
    const float* __restrict__ wq, const float* __restrict__ wkv,
    const float* __restrict__ ffw1,
    const float* __restrict__ nl_b, const float* __restrict__ nm_b,
    const float* __restrict__ ffn_b, float* __restrict__ bias)
{
    int l = blockIdx.z;
    int o = blockIdx.x * 256 + threadIdx.x;
    int k0 = blockIdx.y * 128;
    const float* W; const float* bv; int n, Nd;
    if (o < 512)       { W = wq   + (long)l * D * INNER;     bv = nl_b  + (long)l * D; n = o;        Nd = INNER; }
    else if (o < 1536) { W = wkv  + (long)l * D * 2 * INNER; bv = nl_b  + (long)l * D; n = o - 512;  Nd = 2 * INNER; }
    else if (o < 2560) { W = wkv  + (long)l * D * 2 * INNER; bv = nm_b  + (long)l * D; n = o - 1536; Nd = 2 * INNER; }
    else               { W = ffw1 + (long)l * D * 4 * D;     bv = ffn_b + (long)l * D; n = o - 2560; Nd = 4 * D; }
    float s = 0.f;
#pragma unroll 4
    for (int k = k0; k < k0 + 128; ++k)
        s += bv[k] * W[(long)k * Nd + n];
    unsafeAtomicAdd(&bias[(long)l * NBIAS + o], s);
}

// ---------- weight convert via LDS transpose, g-scale folded in --------------
constexpr long WL_LAT = 1536L * 1024;
constexpr long WL_KVX = 1024L * 1024;
constexpr long WL_WO  = 1024L * 512;
constexpr long WL_F1  = 4096L * 1024;
constexpr long WL_F2  = 1024L * 4096;
constexpr long WL_SZ  = WL_LAT + WL_KVX + WL_WO + WL_F1 + WL_F2;  // 11,534,336

__device__ __forceinline__ void conv_tile64(
    const float* __restrict__ src, unsigned short* __restrict__ dst,
    int Kd, int Nd, int tn, int tk, const float* __restrict__ g, float* lds)
{
    int t = threadIdx.x;
    int n0 = tn * 64, k0 = tk * 64;
#pragma unroll
    for (int p = 0; p < 16; ++p) {
        int idx = p * 256 + t;
        int kr = idx >> 6, nc = idx & 63;
        float val = src[(long)(k0 + kr) * Nd + n0 + nc];
        if (g) val *= g[k0 + kr];
        lds[nc * 65 + kr] = val;
    }
    __syncthreads();
#pragma unroll
    for (int p = 0; p < 2; ++p) {
        int nl_ = p * 32 + (t >> 3);
        int kc  = t & 7;
        unsigned short u[8];
#pragma unroll
        for (int j = 0; j < 8; ++j)
            u[j] = f2bf(lds[nl_ * 65 + kc * 8 + j]);
        *(uint4*)(dst + (long)(n0 + nl_) * Kd + k0 + kc * 8) = *(uint4*)u;
    }
}

__global__ __launch_bounds__(256) void wt_conv_all_kernel(
    const float* __restrict__ wq, const float* __restrict__ wkv,
    const float* __restrict__ wo, const float* __restrict__ ffw1,
    const float* __restrict__ ffw2,
    const float* __restrict__ nl_g, const float* __restrict__ nm_g,
    const float* __restrict__ ffn_g,
    unsigned short* __restrict__ wbuf, long wstride, int layer0)
{
    __shared__ float lds[64 * 65];
    int l = layer0 + blockIdx.y;
    unsigned short* wl = wbuf + (long)blockIdx.y * wstride;
    const float* wq_l   = wq   + (long)l * D * INNER;
    const float* wkv_l  = wkv  + (long)l * D * 2 * INNER;
    const float* wo_l   = wo   + (long)l * INNER * D;
    const float* ffw1_l = ffw1 + (long)l * D * 4 * D;
    const float* ffw2_l = ffw2 + (long)l * 4 * D * D;
    const float* nlg = nl_g + (long)l * D;
    const float* nmg = nm_g + (long)l * D;
    const float* ffg = ffn_g + (long)l * D;

    int T = blockIdx.x;
    if (T < 128) {
        conv_tile64(wq_l, wl, D, INNER, T & 7, T >> 3, nlg, lds);
    } else if (T < 384) {
        int Ti = T - 128;
        conv_tile64(wkv_l, wl + 512L * D, D, 2 * INNER, Ti & 15, Ti >> 4, nlg, lds);
    } else if (T < 640) {
        int Ti = T - 384;
        conv_tile64(wkv_l, wl + WL_LAT, D, 2 * INNER, Ti & 15, Ti >> 4, nmg, lds);
    } else if (T < 768) {
        int Ti = T - 640;
        conv_tile64(wo_l, wl + WL_LAT + WL_KVX, INNER, D, Ti & 15, Ti >> 4, nullptr, lds);
    } else if (T < 1792) {
        int Ti = T - 768;
        conv_tile64(ffw1_l, wl + WL_LAT + WL_KVX + WL_WO, D, 4 * D, Ti & 63, Ti >> 6, ffg, lds);
    } else {
        int Ti = T - 1792;
        conv_tile64(ffw2_l, wl + WL_LAT + WL_KVX + WL_WO + WL_F1, 4 * D, D, Ti & 15, Ti >> 4, nullptr, lds);
    }
}

// --------------------- wave-tile bf16 GEMM core ------------------------------
__device__ __forceinline__ void load_set(
    const unsigned short* __restrict__ ap, const unsigned short* __restrict__ bp,
    long rs, int ko, bf16x8 (&av)[4], bf16x8 (&bv)[4])
{
#pragma unroll
    for (int q = 0; q < 4; ++q) {
        av[q] = *(const bf16x8*)(ap + q * rs + ko);
        bv[q] = *(const bf16x8*)(bp + q * rs + ko);
    }
}

__device__ __forceinline__ void mfma_set(
    const bf16x8 (&av)[4], const bf16x8 (&bv)[4], f32x4 (&acc)[4][4])
{
#pragma unroll
    for (int mm = 0; mm < 4; ++mm)
#pragma unroll
        for (int nn = 0; nn < 4; ++nn)
            acc[mm][nn] = __builtin_amdgcn_mfma_f32_16x16x32_bf16(av[mm], bv[nn], acc[mm][nn], 0, 0, 0);
}

__device__ __forceinline__ void gemm_core(
    const unsigned short* __restrict__ ap, const unsigned short* __restrict__ bp,
    long rs, int Kc, f32x4 (&acc)[4][4])
{
    bf16x8 aC[4], bC[4], aN[4], bN[4];
    load_set(ap, bp, rs, 0, aC, bC);
    for (int ko = 0; ko < Kc; ko += 64) {
        load_set(ap, bp, rs, ko + 32, aN, bN);
        mfma_set(aC, bC, acc);
        if (ko + 64 < Kc)
            load_set(ap, bp, rs, ko + 64, aC, bC);
        mfma_set(aN, bN, acc);
    }
}

// ---- 2-wave in-block K-split reduce: wave1 -> LDS, wave0 adds --------------
__device__ __forceinline__ bool ksplit_reduce(
    f32x4 (&acc)[4][4], float* red, int w, int lg, int lr)
{
    if (w == 1) {
#pragma unroll
        for (int mm = 0; mm < 4; ++mm)
#pragma unroll
            for (int nn = 0; nn < 4; ++nn)
#pragma unroll
                for (int r = 0; r < 4; ++r)
                    red[(mm * 16 + lg * 4 + r) * 65 + nn * 16 + lr] = acc[mm][nn][r];
    }
    __syncthreads();
    if (w == 0) {
#pragma unroll
        for (int mm = 0; mm < 4; ++mm)
#pragma unroll
            for (int nn = 0; nn < 4; ++nn)
#pragma unroll
                for (int r = 0; r < 4; ++r)
                    acc[mm][nn][r] += red[(mm * 16 + lg * 4 + r) * 65 + nn * 16 + lr];
        return true;
    }
    return false;
}

// --------- kv-x tile (1-wave): kb(j=i)/vt from xhat @ wkvxT + bias -----------
__device__ __forceinline__ void kvx_tile(
    int Ti, const unsigned short* __restrict__ xhat,
    const unsigned short* __restrict__ wkvxT, const float* __restrict__ bias_x,
    unsigned short* __restrict__ kb, unsigned short* __restrict__ vt, int lane)
{
    int lr = lane & 15, lg = lane >> 4;
    int bm = Ti % 66, bn = Ti / 66;
    long m0 = (long)bm * 64, n0 = (long)bn * 64;

    const unsigned short* ap = xhat + (m0 + lr) * D + lg * 8;
    const unsigned short* bp = wkvxT + (n0 + lr) * D + lg * 8;
    f32x4 acc[4][4] = {};
    gemm_core(ap, bp, 16L * D, D, acc);

#pragma unroll
    for (int mm = 0; mm < 4; ++mm) {
        long ar0 = m0 + mm * 16 + lg * 4;
        if (ar0 >= MX) continue;
#pragma unroll
        for (int nn = 0; nn < 4; ++nn) {
            long col = n0 + nn * 16 + lr;   // 0..1023
            float bcol = bias_x[col];
            f32x4 v = acc[mm][nn];
#pragma unroll
            for (int r = 0; r < 4; ++r) v[r] += bcol;
            if (col < 512) {                 // K-part
#pragma unroll
                for (int r = 0; r < 4; ++r) {
                    long ar = ar0 + r;
                    int bb = ar >= F;
                    long i = ar - (bb ? F : 0);
                    kb[((long)bb * FN_PAD + i) * INNER + col] = f2bf(v[r]);
                }
            } else {                         // V-part (transposed)
                int d = (int)col - 512;
                int bb0 = ar0 >= F;
                int bb3 = (ar0 + 3) >= F;
                long i0 = ar0 - (bb0 ? F : 0);
                if ((bb0 == bb3) && ((i0 & 3) == 0)) {
                    ushort4 pk;
                    pk.x = f2bf(v[0]); pk.y = f2bf(v[1]);
                    pk.z = f2bf(v[2]); pk.w = f2bf(v[3]);
                    *(ushort4*)(vt + ((long)bb0 * INNER + d) * FN_PAD + i0) = pk;
                } else {
#pragma unroll
                    for (int r = 0; r < 4; ++r) {
                        long ar = ar0 + r;
                        int bb = ar >= F;
                        long i = ar - (bb ? F : 0);
                        vt[((long)bb * INNER + d) * FN_PAD + i] = f2bf(v[r]);
                    }
                }
            }
        }
    }
}

__global__ __launch_bounds__(64) void kvx_kernel(
    const unsigned short* __restrict__ xhat, const unsigned short* __restrict__ wkvxT,
    const float* __restrict__ bias_x,
    unsigned short* __restrict__ kb, unsigned short* __restrict__ vt)
{
    kvx_tile(xcd_swz(blockIdx.x, NT_KVX), xhat, wkvxT, bias_x, kb, vt, threadIdx.x);
}

// --------- latent q/kv projection (2-wave k-split), 552 tiles ----------------
__global__ __launch_bounds__(128) void qlat_kernel(
    const unsigned short* __restrict__ la,
    const unsigned short* __restrict__ wlatT, const float* __restrict__ bias_l,
    unsigned short* __restrict__ qb, unsigned short* __restrict__ kb,
    unsigned short* __restrict__ vt)
{
    __shared__ float red[64 * 65];
    int tid = threadIdx.x;
    int w = tid >> 6, lane = tid & 63;
    int lr = lane & 15, lg = lane >> 4;

    int T = xcd_swz(blockIdx.x, 552);
    int bm = T % 23, bn = T / 23;
    long m0 = (long)bm * 64, n0 = (long)bn * 64;

    const unsigned short* ap = la    + (m0 + lr) * D + w * 512 + lg * 8;
    const unsigned short* bp = wlatT + (n0 + lr) * D + w * 512 + lg * 8;
    f32x4 acc[4][4] = {};
    gemm_core(ap, bp, 16L * D, 512, acc);

    if (!ksplit_reduce(acc, red, w, lg, lr)) return;

#pragma unroll
    for (int mm = 0; mm < 4; ++mm) {
        long ar0 = m0 + mm * 16 + lg * 4;
        if (ar0 >= MLAT) continue;
#pragma unroll
        for (int nn = 0; nn < 4; ++nn) {
            long col = n0 + nn * 16 + lr;
            float bcol = bias_l[col];
            f32x4 v = acc[mm][nn];
#pragma unroll
            for (int r = 0; r < 4; ++r) v[r] += bcol;
            if (col < 512) {                // q
#pragma unroll
                for (int r = 0; r < 4; ++r) {
                    long ar = ar0 + r;
                    if (ar < MLAT) {
                        int bb = ar >= NL;
                        long i = ar - (bb ? NL : 0);
                        qb[((long)bb * NL_PAD + i) * INNER + col] = f2bf(v[r] * 0.125f);
                    }
                }
            } else {
                int c = (int)col - 512;     // 0..1023
                if (c < 512) {              // K-part (j = F+i)
#pragma unroll
                    for (int r = 0; r < 4; ++r) {
                        long ar = ar0 + r;
                        if (ar < MLAT) {
                            int bb = ar >= NL;
                            long i = ar - (bb ? NL : 0);
                            kb[((long)bb * FN_PAD + F + i) * INNER + c] = f2bf(v[r]);
                        }
                    }
                } else {                    // V-part (transposed, j = F+i)
                    int d = c - 512;
                    int bb0 = ar0 >= NL;
                    int bb3 = (ar0 + 3) >= NL;
                    long i0 = ar0 - (bb0 ? NL : 0);
                    long j0 = F + i0;
                    if ((ar0 + 3 < MLAT) && (bb0 == bb3) && ((j0 & 3) == 0)) {
                        ushort4 pk;
                        pk.x = f2bf(v[0]); pk.y = f2bf(v[1]);
                        pk.z = f2bf(v[2]); pk.w = f2bf(v[3]);
                        *(ushort4*)(vt + ((long)bb0 * INNER + d) * FN_PAD + j0) = pk;
                    } else {
#pragma unroll
                        for (int r = 0; r < 4; ++r) {
                            long ar = ar0 + r;
                            if (ar < MLAT) {
                                int bb = ar >= NL;
                                long i = ar - (bb ? NL : 0);
                                vt[((long)bb * INNER + d) * FN_PAD + F + i] = f2bf(v[r]);
                            }
                        }
                    }
                }
            }
        }
    }
}

// ------------- ffw1 GEMM: 2-wave k-split, GELU+bias epilogue ----------------
__global__ __launch_bounds__(128) void gemm_gelu2_kernel(
    const unsigned short* __restrict__ A, const unsigned short* __restrict__ Bt,
    unsigned short* __restrict__ C, const float* __restrict__ bias,
    int M, int K, int ldc, int bmN)
{
    __shared__ float red[64 * 65];
    int tid = threadIdx.x;
    int w = tid >> 6, lane = tid & 63;
    int lr = lane & 15, lg = lane >> 4;
    int u = xcd_swz(blockIdx.x, gridDim.x);
    int bm = u % bmN, bn = u / bmN;
    long m0 = (long)bm * 64, n0 = (long)bn * 64;
    int kh = K >> 1;

    const unsigned short* ap = A  + (m0 + lr) * K + w * kh + lg * 8;
    const unsigned short* bp = Bt + (n0 + lr) * K + w * kh + lg * 8;
    f32x4 acc[4][4] = {};
    gemm_core(ap, bp, 16L * K, kh, acc);

    if (!ksplit_reduce(acc, red, w, lg, lr)) return;

#pragma unroll
    for (int mm = 0; mm < 4; ++mm) {
        long ar0 = m0 + mm * 16 + lg * 4;
        if (ar0 >= M) continue;
#pragma unroll
        for (int nn = 0; nn < 4; ++nn) {
            long col = n0 + nn * 16 + lr;
            float bcol = bias[col];
            f32x4 v = acc[mm][nn];
#pragma unroll
            for (int r = 0; r < 4; ++r)
                if (ar0 + r < M) {
                    float val = v[r] + bcol;
                    val = 0.5f * val * (1.0f + erff(val * 0.70710678118654752f));
                    C[(ar0 + r) * (long)ldc + col] = f2bf(val);
                }
        }
    }
}

// ---------- split-K RESA GEMM tile (used by wo and ffw2 paths) ---------------
__device__ __forceinline__ void resa_tile(
    int u, const unsigned short* __restrict__ A, const unsigned short* __restrict__ Bt,
    float* __restrict__ C, int M, int K, int Kc, int ldc, int bmN, int bnN, int lane)
{
    int lr = lane & 15, lg = lane >> 4;
    int bm = u % bmN;
    int t2 = u / bmN;
    int bn = t2 % bnN;
    int kz = t2 / bnN;
    long m0 = (long)bm * 64;
    long n0 = (long)bn * 64;
    int k0 = kz * Kc;

    const unsigned short* ap = A  + (m0 + lr) * K + k0 + lg * 8;
    const unsigned short* bp = Bt + (n0 + lr) * K + k0 + lg * 8;
    f32x4 acc[4][4] = {};
    gemm_core(ap, bp, 16L * K, Kc, acc);

#pragma unroll
    for (int mm = 0; mm < 4; ++mm) {
        long ar0 = m0 + mm * 16 + lg * 4;
        if (ar0 >= M) continue;
#pragma unroll
        for (int nn = 0; nn < 4; ++nn) {
            long col = n0 + nn * 16 + lr;
            f32x4 v = acc[mm][nn];
#pragma unroll
            for (int r = 0; r < 4; ++r)
                if (ar0 + r < M)
                    unsafeAtomicAdd(&C[(ar0 + r) * (long)ldc + col], v[r]);
        }
    }
}

__global__ __launch_bounds__(64) void gemm_split_kernel(
    const unsigned short* __restrict__ A, const unsigned short* __restrict__ Bt,
    float* __restrict__ C, int M, int K, int Kc, int ldc, int bmN, int bnN)
{
    resa_tile(xcd_swz(blockIdx.x, gridDim.x), A, Bt, C, M, K, Kc, ldc, bmN, bnN, threadIdx.x);
}

// ----- merged ffw2(layer l) + kv-x(layer l+1): one dispatch, two tile types --
__global__ __launch_bounds__(64) void ffw2_kvx_kernel(
    const unsigned short* __restrict__ h1b, const unsigned short* __restrict__ f2T,
    float* __restrict__ lat,
    const unsigned short* __restrict__ xhat, const unsigned short* __restrict__ wkvxT_n,
    const float* __restrict__ bias_xn,
    unsigned short* __restrict__ kb, unsigned short* __restrict__ vt)
{
    int T = xcd_swz(blockIdx.x, gridDim.x);
    if (T < NT_FFW2)
        resa_tile(T, h1b, f2T, lat, MLAT, 4 * D, 512, D, 23, 16, threadIdx.x);
    else
        kvx_tile(T - NT_FFW2, xhat, wkvxT_n, bias_xn, kb, vt, threadIdx.x);
}

// ------------- MFMA flash attention, split-KV, flat grid + XCD chunking ------
__global__ __launch_bounds__(256) void attn_split_kernel(
    const unsigned short* __restrict__ qb, const unsigned short* __restrict__ kb,
    const unsigned short* __restrict__ vt, const int* __restrict__ split,
    float* __restrict__ po, float* __restrict__ pml, int skv)
{
    int u = xcd_swz(blockIdx.x, gridDim.x);
    int q64  = u % 12;
    int bh   = (u / 12) % NBH;
    int sidx = u / (12 * NBH);
    int b  = bh >> 3;
    int h  = bh & 7;
    int w  = threadIdx.x >> 6;
    int lane = threadIdx.x & 63;
    int q0 = q64 * 64 + w * 16;
    if (q0 >= NL) return;

    __shared__ unsigned short p_lds[4][16 * 64];   // 2KB per wave, XOR-swizzled
    unsigned short* pl = p_lds[w];

    int lr = lane & 15;
    int lg = lane >> 4;

    bf16x8 qa0, qa1;
    {
        const unsigned short* qrow = qb + ((long)b * NL_PAD + q0 + lr) * INNER + h * 64;
        qa0 = *(const bf16x8*)(qrow + lg * 8);
        qa1 = *(const bf16x8*)(qrow + 32 + lg * 8);
    }

    f32x4 oacc[4] = {{0,0,0,0},{0,0,0,0},{0,0,0,0},{0,0,0,0}};
    float m[4]    = {-1e30f, -1e30f, -1e30f, -1e30f};
    float lsum[4] = {0.f, 0.f, 0.f, 0.f};

    int sp = split[b];
    if (sp < 0) sp = 0;
    if (sp > F) sp = F;
    int ntx = (sp + 63) >> 6;
    int ntot = ntx + 12;
    int t0 = (ntot * sidx) / skv;
    int t1 = (ntot * (sidx + 1)) / skv;

    for (int t = t0; t < t1; ++t) {
        int j0, limit;
        if (t < ntx) { j0 = t * 64;             limit = sp; }
        else         { j0 = F + (t - ntx) * 64; limit = FN; }

        f32x4 s[4] = {{0,0,0,0},{0,0,0,0},{0,0,0,0},{0,0,0,0}};
        const unsigned short* kbase =
            kb + ((long)b * FN_PAD + j0 + lr) * INNER + h * 64 + lg * 8;
#pragma unroll
        for (int st = 0; st < 4; ++st) {
            bf16x8 kf0 = *(const bf16x8*)(kbase + (long)st * 16 * INNER);
            bf16x8 kf1 = *(const bf16x8*)(kbase + (long)st * 16 * INNER + 32);
            s[st] = __builtin_amdgcn_mfma_f32_16x16x32_bf16(qa0, kf0, s[st], 0, 0, 0);
            s[st] = __builtin_amdgcn_mfma_f32_16x16x32_bf16(qa1, kf1, s[st], 0, 0, 0);
        }

        if (j0 + 64 > limit) {
#pragma unroll
            for (int st = 0; st < 4; ++st) {
                bool valid = (j0 + st * 16 + lr) < limit;
#pragma unroll
                for (int r = 0; r < 4; ++r)
                    s[st][r] = valid ? s[st][r] : -1e30f;
            }
        }

        float tm[4];
#pragma unroll
        for (int r = 0; r < 4; ++r)
            tm[r] = fmaxf(fmaxf(s[0][r], s[1][r]), fmaxf(s[2][r], s[3][r]));
#pragma unroll
        for (int off = 1; off < 16; off <<= 1) {
#pragma unroll
            for (int r = 0; r < 4; ++r)
                tm[r] = fmaxf(tm[r], __shfl_xor(tm[r], off));
        }
        float cr[4];
#pragma unroll
        for (int r = 0; r < 4; ++r) {
            float mn = fmaxf(m[r], tm[r]);
            cr[r] = __expf(m[r] - mn);
            m[r]  = mn;
        }
#pragma unroll
        for (int st = 0; st < 4; ++st)
#pragma unroll
            for (int r = 0; r < 4; ++r)
                s[st][r] = __expf(s[st][r] - m[r]);
        float ts[4];
#pragma unroll
        for (int r = 0; r < 4; ++r)
            ts[r] = (s[0][r] + s[1][r]) + (s[2][r] + s[3][r]);
#pragma unroll
        for (int off = 1; off < 16; off <<= 1) {
#pragma unroll
            for (int r = 0; r < 4; ++r)
                ts[r] += __shfl_xor(ts[r], off);
        }
#pragma unroll
        for (int r = 0; r < 4; ++r)
            lsum[r] = lsum[r] * cr[r] + ts[r];
#pragma unroll
        for (int nst = 0; nst < 4; ++nst)
#pragma unroll
            for (int r = 0; r < 4; ++r)
                oacc[nst][r] *= cr[r];

#pragma unroll
        for (int st = 0; st < 4; ++st)
#pragma unroll
            for (int r = 0; r < 4; ++r) {
                int row  = lg * 4 + r;
                int col  = st * 16 + lr;
                int byte = (row * 128 + col * 2) ^ ((row & 7) << 4);
                *(unsigned short*)((char*)pl + byte) = f2bf(s[st][r]);
            }

#pragma unroll
        for (int kk = 0; kk < 2; ++kk) {
            int row  = lr;
            int byte = (row * 128 + kk * 64 + lg * 16) ^ ((row & 7) << 4);
            bf16x8 pa = *(const bf16x8*)((char*)pl + byte);
#pragma unroll
            for (int nst = 0; nst < 4; ++nst) {
                const unsigned short* vp =
                    vt + ((long)bh * DH + nst * 16 + lr) * FN_PAD + j0 + kk * 32 + lg * 8;
                bf16x8 vf = *(const bf16x8*)vp;
                oacc[nst] = __builtin_amdgcn_mfma_f32_16x16x32_bf16(pa, vf, oacc[nst], 0, 0, 0);
            }
        }
    }

    long base = ((long)sidx * NBH + bh) * NL_PAD;
#pragma unroll
    for (int nst = 0; nst < 4; ++nst)
#pragma unroll
        for (int r = 0; r < 4; ++r) {
            int row = q0 + lg * 4 + r;
            if (row < NL)
                po[(base + row) * DH + nst * 16 + lr] = oacc[nst][r];
        }
    if (lr == 0) {
#pragma unroll
        for (int r = 0; r < 4; ++r) {
            int row = q0 + lg * 4 + r;
            if (row < NL) {
                pml[(base + row) * 2 + 0] = m[r];
                pml[(base + row) * 2 + 1] = lsum[r];
            }
        }
    }
}

// -------- combine skv partials -> ob bf16 (one wave per (b,h,i) row) --------
__global__ __launch_bounds__(256) void attn_combine_kernel(
    const float* __restrict__ po, const float* __restrict__ pml,
    unsigned short* __restrict__ o, int skv)
{
    int row = blockIdx.x * 4 + (threadIdx.x >> 6);
    if (row >= NBH * NL) return;
    int lane = threadIdx.x & 63;
    int bh = row / NL;
    int i  = row - bh * NL;
    int b = bh >> 3, h = bh & 7;

    float m = -1e30f, l = 0.0f, acc = 0.0f;
    for (int s = 0; s < skv; ++s) {
        long base = ((long)s * NBH + bh) * NL_PAD + i;
        float ms = pml[base * 2 + 0];
        float ls = pml[base * 2 + 1];
        float os = po[base * DH + lane];
        float mn = fmaxf(m, ms);
        float c1 = __expf(m - mn);
        float c2 = __expf(ms - mn);
        acc = acc * c1 + os * c2;
        l   = l * c1 + ls * c2;
        m   = mn;
    }
    o[((long)b * NL + i) * INNER + h * 64 + lane] = f2bf(acc / l);
}

// ------------------------------- host side ----------------------------------
extern "C" void kernel_launch(void* const* d_in, const int* in_sizes, int n_in,
                              void* d_out, int out_size, void* d_ws, size_t ws_size,
                              hipStream_t stream)
{
    const float* x        = (const float*)d_in[0];
    const int*   split    = (const int*)d_in[1];
    const float* latents  = (const float*)d_in[2];
    const float* sp_emb   = (const float*)d_in[3];
    const float* fr_emb   = (const float*)d_in[4];
    const float* nm_g     = (const float*)d_in[5];
    const float* nm_b     = (const float*)d_in[6];
    const float* nl_g     = (const float*)d_in[7];
    const float* nl_b     = (const float*)d_in[8];
    const float* wq       = (const float*)d_in[9];
    const float* wkv      = (const float*)d_in[10];
    const float* wo       = (const float*)d_in[11];
    const float* ffn_g    = (const float*)d_in[12];
    const float* ffn_b    = (const float*)d_in[13];
    const float* ffw1     = (const float*)d_in[14];
    const float* ffw2     = (const float*)d_in[15];
    const float* final_g  = (const float*)d_in[16];
    const float* final_b  = (const float*)d_in[17];
    float* out = (float*)d_out;

    // ---- cursor-based workspace layout ----
    char* cur = (char*)d_ws;
    auto alloc = [&](size_t bytes) {
        void* p = (void*)cur;
        cur += (bytes + 255) & ~(size_t)255;
        return p;
    };

    unsigned short* xhat = (unsigned short*)alloc((long)MX * D * 2);
    float* lat  = (float*)alloc((long)B * NL * D * 4);
    unsigned short* la  = (unsigned short*)alloc((long)MLAT_PAD * D * 2);
    unsigned short* fa  = (unsigned short*)alloc((long)MLAT_PAD * D * 2);
    unsigned short* h1b = (unsigned short*)alloc((long)MLAT_PAD * 4 * D * 2);
    unsigned short* ob  = (unsigned short*)alloc((long)MLAT_PAD * INNER * 2);
    unsigned short* qb  = (unsigned short*)alloc((long)B * NL_PAD * INNER * 2);
    unsigned short* kb  = (unsigned short*)alloc((long)B * FN_PAD * INNER * 2);
    unsigned short* vt  = (unsigned short*)alloc((long)B * FN_PAD * INNER * 2);
    float* bias = (float*)alloc((long)DEPTH * NBIAS * 4);
    float* pml  = (float*)alloc((long)SKVMAX * NBH * NL_PAD * 2 * 4);

    size_t fixed = (size_t)(cur - (char*)d_ws);
    const size_t po8 = ((size_t)8 * NBH * NL_PAD * DH * 4 + 255) & ~(size_t)255;
    const size_t po4 = ((size_t)4 * NBH * NL_PAD * DH * 4 + 255) & ~(size_t)255;
    const size_t wb6 = ((size_t)6 * WL_SZ * 2 + 255) & ~(size_t)255;
    const size_t wb1 = ((size_t)WL_SZ * 2 + 255) & ~(size_t)255;
    const size_t margin = 4096;

    int skv;
    bool hoist_w;
    if (fixed + po8 + wb6 + margin <= ws_size)      { skv = 8; hoist_w = true;  }
    else if (fixed + po4 + wb6 + margin <= ws_size) { skv = 4; hoist_w = true;  }
    else if (fixed + po8 + wb1 + margin <= ws_size) { skv = 8; hoist_w = false; }
    else                                            { skv = 4; hoist_w = false; }

    float* po = (float*)alloc(skv == 8 ? po8 : po4);
    unsigned short* wbuf = (unsigned short*)alloc(hoist_w ? wb6 : wb1);

    hipMemsetAsync(bias, 0, (size_t)DEPTH * NBIAS * 4, stream);

    emb_ln_kernel<<<MX, 256, 0, stream>>>(x, sp_emb, fr_emb, xhat);
    lat_init_kernel<<<B * NL, 256, 0, stream>>>(latents, lat);
    bias_kernel<<<dim3(NBIAS / 256, 8, 6), 256, 0, stream>>>(
        wq, wkv, ffw1, nl_b, nm_b, ffn_b, bias);

    if (hoist_w)
        wt_conv_all_kernel<<<dim3(2816, 6), 256, 0, stream>>>(
            wq, wkv, wo, ffw1, ffw2, nl_g, nm_g, ffn_g, wbuf, WL_SZ, 0);

    // layer-0 kv-x: off the serial chain, run once up front (hoisted path)
    if (hoist_w)
        kvx_kernel<<<NT_KVX, 64, 0, stream>>>(xhat, wbuf + WL_LAT, bias + 1536, kb, vt);

    for (int l = 0; l < DEPTH; ++l) {
        unsigned short* wl = wbuf + (hoist_w ? (long)l * WL_SZ : 0);
        if (!hoist_w) {
            wt_conv_all_kernel<<<dim3(2816, 1), 256, 0, stream>>>(
                wq, wkv, wo, ffw1, ffw2, nl_g, nm_g, ffn_g, wbuf, 0, l);
            kvx_kernel<<<NT_KVX, 64, 0, stream>>>(
                xhat, wl + WL_LAT, bias + (long)l * NBIAS + 1536, kb, vt);
        }

        unsigned short* wlatT = wl;
        unsigned short* woT   = wl + WL_LAT + WL_KVX;
        unsigned short* f1T   = wl + WL_LAT + WL_KVX + WL_WO;
        unsigned short* f2T   = wl + WL_LAT + WL_KVX + WL_WO + WL_F1;
        const float* bias_l = bias + (long)l * NBIAS;

        // la = plain LN(lat)
        rownorm_plain_kernel<<<MLAT, 256, 0, stream>>>(lat, la);

        // latent q/kv projection only (552 two-wave k-split tiles)
        qlat_kernel<<<552, 128, 0, stream>>>(la, wlatT, bias_l, qb, kb, vt);

        // attention: split-KV partials + combine
        attn_split_kernel<<<12 * NBH * skv, 256, 0, stream>>>(
            qb, kb, vt, split, po, pml, skv);
        attn_combine_kernel<<<(NBH * NL + 3) / 4, 256, 0, stream>>>(po, pml, ob, skv);

        // lat += ob @ wo   (split-K = 4)
        gemm_split_kernel<<<23 * 16 * 4, 64, 0, stream>>>(
            ob, woT, lat, MLAT, INNER, 128, D, 23, 16);

        // FFN: fa = plain LN(lat); h1 = gelu(fa@f1T + bias)
        rownorm_plain_kernel<<<MLAT, 256, 0, stream>>>(lat, fa);
        gemm_gelu2_kernel<<<23 * 64, 128, 0, stream>>>(
            fa, f1T, h1b, bias_l + 2560, MLAT, D, 4 * D, 23);

        // lat += h1 @ f2T, merged with next layer's kv-x (hoisted path)
        if (hoist_w && l + 1 < DEPTH) {
            unsigned short* wkvx_n = wbuf + (long)(l + 1) * WL_SZ + WL_LAT;
            const float* bias_xn = bias + (long)(l + 1) * NBIAS + 1536;
            ffw2_kvx_kernel<<<NT_FFW2 + NT_KVX, 64, 0, stream>>>(
                h1b, f2T, lat, xhat, wkvx_n, bias_xn, kb, vt);
        } else {
            gemm_split_kernel<<<NT_FFW2, 64, 0, stream>>>(
                h1b, f2T, lat, MLAT, 4 * D, 512, D, 23, 16);
        }
    }

    final_ln_kernel<<<MLAT, 256, 0, stream>>>(lat, final_g, final_b, out);
}

// Round 19
// 1865.498 us; speedup vs baseline: 1.1038x; 1.1038x over previous
//
#include <hip/hip_runtime.h>
#include <math.h>

constexpr int B = 2;
constexpr int F = 2112;
constexpr int D = 1024;
constexpr int H = 8;
constexpr int DH = 64;
constexpr int INNER = H * DH;      // 512
constexpr int NL = 721;
constexpr int NL_PAD = 768;
constexpr int MLAT = B * NL;       // 1442
constexpr int MLAT_PAD = 1536;
constexpr int VD = 64;
constexpr int DEPTH = 6;
constexpr int FN = F + NL;         // 2833
constexpr int FN_PAD = 2880;       // 45 * 64
constexpr int NBH = B * H;         // 16
constexpr int SKVMAX = 8;
constexpr int MX = B * F;          // 4224
constexpr int NBIAS = 6656;        // 512(q) + 1024(kv-lat) + 1024(kv-x) + 4096(ffn)
constexpr float EPS = 1e-5f;

typedef __bf16 bf16x8 __attribute__((ext_vector_type(8)));
typedef float  f32x4  __attribute__((ext_vector_type(4)));

static __device__ __forceinline__ unsigned short f2bf(float f)
{
    union { float f; unsigned int u; } x; x.f = f;
    unsigned int r = x.u + 0x7FFFu + ((x.u >> 16) & 1u);   // RNE
    return (unsigned short)(r >> 16);
}
static __device__ __forceinline__ float bf2f(unsigned short u)
{
    union { unsigned int i; float f; } x; x.i = ((unsigned int)u) << 16; return x.f;
}

// XCD-chunked bijective block->tile mapping. Requires nt % 8 == 0.
static __device__ __forceinline__ int xcd_swz(int b, int nt)
{
    return (b & 7) * (nt >> 3) + (b >> 3);
}

// ---------------- block reduce (sum, sumsq) over 256 threads ----------------
__device__ __forceinline__ void block_reduce_2(float& s, float& ss, float* red)
{
#pragma unroll
    for (int off = 32; off; off >>= 1) {
        s  += __shfl_xor(s, off);
        ss += __shfl_xor(ss, off);
    }
    int wv = threadIdx.x >> 6;
    if ((threadIdx.x & 63) == 0) { red[wv] = s; red[4 + wv] = ss; }
    __syncthreads();
    s  = red[0] + red[1] + red[2] + red[3];
    ss = red[4] + red[5] + red[6] + red[7];
}

// ------- x + spatial_emb + frame_emb, then row-normalize -> bf16 xhat -------
__global__ __launch_bounds__(256) void emb_ln_kernel(
    const float* __restrict__ x, const float* __restrict__ sp_emb,
    const float* __restrict__ fr_emb, unsigned short* __restrict__ xhat)
{
    __shared__ float red[8];
    int r = blockIdx.x;            // r = b*F + j
    int j = r % F;
    int t = threadIdx.x;
    const float4* xr = (const float4*)(x + (long)r * D);
    int spr = (j < VD) ? j : VD;
    int frr = (j < VD) ? 0 : (j - VD + 1);
    const float4* sp4 = (const float4*)(sp_emb + (long)spr * D);
    const float4* fr4 = (const float4*)(fr_emb + (long)frr * D);
    float4 v = xr[t], a = sp4[t], c = fr4[t];
    v.x += a.x + c.x; v.y += a.y + c.y; v.z += a.z + c.z; v.w += a.w + c.w;
    float s  = v.x + v.y + v.z + v.w;
    float ss = v.x*v.x + v.y*v.y + v.z*v.z + v.w*v.w;
    block_reduce_2(s, ss, red);
    float mean = s * (1.0f / D);
    float var  = ss * (1.0f / D) - mean * mean;
    float rstd = rsqrtf(var + EPS);
    ushort4 o;
    o.x = f2bf((v.x - mean) * rstd);
    o.y = f2bf((v.y - mean) * rstd);
    o.z = f2bf((v.z - mean) * rstd);
    o.w = f2bf((v.w - mean) * rstd);
    ((ushort4*)(xhat + (long)r * D))[t] = o;
}

// --------------------- plain row-normalize -> bf16 ---------------------------
__global__ __launch_bounds__(256) void rownorm_plain_kernel(
    const float* __restrict__ in, unsigned short* __restrict__ out)
{
    __shared__ float red[8];
    int r = blockIdx.x;
    int t = threadIdx.x;
    float4 v = ((const float4*)(in + (long)r * D))[t];
    float s  = v.x + v.y + v.z + v.w;
    float ss = v.x*v.x + v.y*v.y + v.z*v.z + v.w*v.w;
    block_reduce_2(s, ss, red);
    float mean = s * (1.0f / D);
    float var  = ss * (1.0f / D) - mean * mean;
    float rstd = rsqrtf(var + EPS);
    ushort4 o;
    o.x = f2bf((v.x - mean) * rstd);
    o.y = f2bf((v.y - mean) * rstd);
    o.z = f2bf((v.z - mean) * rstd);
    o.w = f2bf((v.w - mean) * rstd);
    ((ushort4*)(out + (long)r * D))[t] = o;
}

// ------------------------ final LN with affine -> out ------------------------
__global__ __launch_bounds__(256) void final_ln_kernel(
    const float* __restrict__ in, const float* __restrict__ g,
    const float* __restrict__ b, float* __restrict__ out)
{
    __shared__ float red[8];
    int r = blockIdx.x;
    int t = threadIdx.x;
    float4 v = ((const float4*)(in + (long)r * D))[t];
    float s  = v.x + v.y + v.z + v.w;
    float ss = v.x*v.x + v.y*v.y + v.z*v.z + v.w*v.w;
    block_reduce_2(s, ss, red);
    float mean = s * (1.0f / D);
    float var  = ss * (1.0f / D) - mean * mean;
    float rstd = rsqrtf(var + EPS);
    float4 g4 = ((const float4*)g)[t];
    float4 b4 = ((const float4*)b)[t];
    float4 o;
    o.x = (v.x - mean) * rstd * g4.x + b4.x;
    o.y = (v.y - mean) * rstd * g4.y + b4.y;
    o.z = (v.z - mean) * rstd * g4.z + b4.z;
    o.w = (v.w - mean) * rstd * g4.w + b4.w;
    ((float4*)(out + (long)r * D))[t] = o;
}

// ---------------------- lat init: broadcast latents to B ---------------------
__global__ __launch_bounds__(256) void lat_init_kernel(
    const float* __restrict__ latents, float* __restrict__ lat)
{
    int r = blockIdx.x;            // b*NL + i
    int i = r % NL;
    int t = threadIdx.x;
    ((float4*)(lat + (long)r * D))[t] = ((const float4*)(latents + (long)i * D))[t];
}

// ------------- bias rows: bias[l][o] += b_slice @ W column o -----------------
// split-K over blockIdx.y (8 slices of 128 k), atomic accumulate.
__global__ __launch_bounds__(256) void bias_kernel(
    const float* __restrict__ wq, const float* __restrict__ wkv,
    const float* __restrict__ ffw1,
    const float* __restrict__ nl_b, const float* __restrict__ nm_b,
    const float* __restrict__ ffn_b, float* __restrict__ bias)
{
    int l = blockIdx.z;
    int o = blockIdx.x * 256 + threadIdx.x;
    int k0 = blockIdx.y * 128;
    const float* W; const float* bv; int n, Nd;
    if (o < 512)       { W = wq   + (long)l * D * INNER;     bv = nl_b  + (long)l * D; n = o;        Nd = INNER; }
    else if (o < 1536) { W = wkv  + (long)l * D * 2 * INNER; bv = nl_b  + (long)l * D; n = o - 512;  Nd = 2 * INNER; }
    else if (o < 2560) { W = wkv  + (long)l * D * 2 * INNER; bv = nm_b  + (long)l * D; n = o - 1536; Nd = 2 * INNER; }
    else               { W = ffw1 + (long)l * D * 4 * D;     bv = ffn_b + (long)l * D; n = o - 2560; Nd = 4 * D; }
    float s = 0.f;
#pragma unroll 4
    for (int k = k0; k < k0 + 128; ++k)
        s += bv[k] * W[(long)k * Nd + n];
    unsafeAtomicAdd(&bias[(long)l * NBIAS + o], s);
}

// ---------- weight convert via LDS transpose, g-scale folded in --------------
// dst per layer: [wlatT 1536x1024 (g=nl)] [wkvxT 1024x1024 (g=nm)] [woT 1024x512]
//                [f1T 4096x1024 (g=ffn)] [f2T 1024x4096]
constexpr long WL_LAT = 1536L * 1024;
constexpr long WL_KVX = 1024L * 1024;
constexpr long WL_WO  = 1024L * 512;
constexpr long WL_F1  = 4096L * 1024;
constexpr long WL_F2  = 1024L * 4096;
constexpr long WL_SZ  = WL_LAT + WL_KVX + WL_WO + WL_F1 + WL_F2;  // 11,534,336

// 64x64 tile, 65-pad (conflict-free), g-scale folded (r16-verified: ~80us).
__device__ __forceinline__ void conv_tile64(
    const float* __restrict__ src, unsigned short* __restrict__ dst,
    int Kd, int Nd, int tn, int tk, const float* __restrict__ g, float* lds)
{
    int t = threadIdx.x;
    int n0 = tn * 64, k0 = tk * 64;
#pragma unroll
    for (int p = 0; p < 16; ++p) {
        int idx = p * 256 + t;
        int kr = idx >> 6, nc = idx & 63;
        float val = src[(long)(k0 + kr) * Nd + n0 + nc];
        if (g) val *= g[k0 + kr];
        lds[nc * 65 + kr] = val;
    }
    __syncthreads();
#pragma unroll
    for (int p = 0; p < 2; ++p) {
        int nl_ = p * 32 + (t >> 3);
        int kc  = t & 7;
        unsigned short u[8];
#pragma unroll
        for (int j = 0; j < 8; ++j)
            u[j] = f2bf(lds[nl_ * 65 + kc * 8 + j]);
        *(uint4*)(dst + (long)(n0 + nl_) * Kd + k0 + kc * 8) = *(uint4*)u;
    }
}

__global__ __launch_bounds__(256) void wt_conv_all_kernel(
    const float* __restrict__ wq, const float* __restrict__ wkv,
    const float* __restrict__ wo, const float* __restrict__ ffw1,
    const float* __restrict__ ffw2,
    const float* __restrict__ nl_g, const float* __restrict__ nm_g,
    const float* __restrict__ ffn_g,
    unsigned short* __restrict__ wbuf, long wstride, int layer0)
{
    __shared__ float lds[64 * 65];
    int l = layer0 + blockIdx.y;
    unsigned short* wl = wbuf + (long)blockIdx.y * wstride;
    const float* wq_l   = wq   + (long)l * D * INNER;
    const float* wkv_l  = wkv  + (long)l * D * 2 * INNER;
    const float* wo_l   = wo   + (long)l * INNER * D;
    const float* ffw1_l = ffw1 + (long)l * D * 4 * D;
    const float* ffw2_l = ffw2 + (long)l * 4 * D * D;
    const float* nlg = nl_g + (long)l * D;
    const float* nmg = nm_g + (long)l * D;
    const float* ffg = ffn_g + (long)l * D;

    int T = blockIdx.x;
    if (T < 128) {                      // wq (g=nl): 8n x 16k
        conv_tile64(wq_l, wl, D, INNER, T & 7, T >> 3, nlg, lds);
    } else if (T < 384) {               // wkv (g=nl): 16n x 16k -> wlatT rows 512..
        int Ti = T - 128;
        conv_tile64(wkv_l, wl + 512L * D, D, 2 * INNER, Ti & 15, Ti >> 4, nlg, lds);
    } else if (T < 640) {               // wkv (g=nm) -> wkvxT
        int Ti = T - 384;
        conv_tile64(wkv_l, wl + WL_LAT, D, 2 * INNER, Ti & 15, Ti >> 4, nmg, lds);
    } else if (T < 768) {               // wo: 16n x 8k
        int Ti = T - 640;
        conv_tile64(wo_l, wl + WL_LAT + WL_KVX, INNER, D, Ti & 15, Ti >> 4, nullptr, lds);
    } else if (T < 1792) {              // ffw1 (g=ffn): 64n x 16k
        int Ti = T - 768;
        conv_tile64(ffw1_l, wl + WL_LAT + WL_KVX + WL_WO, D, 4 * D, Ti & 63, Ti >> 6, ffg, lds);
    } else {                            // ffw2: 16n x 64k
        int Ti = T - 1792;
        conv_tile64(ffw2_l, wl + WL_LAT + WL_KVX + WL_WO + WL_F1, 4 * D, D, Ti & 15, Ti >> 4, nullptr, lds);
    }
}

// --------------------- wave-tile bf16 GEMM core ------------------------------
__device__ __forceinline__ void load_set(
    const unsigned short* __restrict__ ap, const unsigned short* __restrict__ bp,
    long rs, int ko, bf16x8 (&av)[4], bf16x8 (&bv)[4])
{
#pragma unroll
    for (int q = 0; q < 4; ++q) {
        av[q] = *(const bf16x8*)(ap + q * rs + ko);
        bv[q] = *(const bf16x8*)(bp + q * rs + ko);
    }
}

__device__ __forceinline__ void mfma_set(
    const bf16x8 (&av)[4], const bf16x8 (&bv)[4], f32x4 (&acc)[4][4])
{
#pragma unroll
    for (int mm = 0; mm < 4; ++mm)
#pragma unroll
        for (int nn = 0; nn < 4; ++nn)
            acc[mm][nn] = __builtin_amdgcn_mfma_f32_16x16x32_bf16(av[mm], bv[nn], acc[mm][nn], 0, 0, 0);
}

__device__ __forceinline__ void gemm_core(
    const unsigned short* __restrict__ ap, const unsigned short* __restrict__ bp,
    long rs, int Kc, f32x4 (&acc)[4][4])
{
    bf16x8 aC[4], bC[4], aN[4], bN[4];
    load_set(ap, bp, rs, 0, aC, bC);
    for (int ko = 0; ko < Kc; ko += 64) {
        load_set(ap, bp, rs, ko + 32, aN, bN);
        mfma_set(aC, bC, acc);
        if (ko + 64 < Kc)
            load_set(ap, bp, rs, ko + 64, aC, bC);
        mfma_set(aN, bN, acc);
    }
}

// ---------------- fused latent-QKV + x-KV projection (1-wave blocks) ---------
// tiles 0..551: A=la (plain LN), Bt=wlatT (nl-folded) -> qb / kb(j=F+i) / vt
// tiles 552..1607: A=xhat, Bt=wkvxT (nm-folded) -> kb(j=i) / vt
__global__ __launch_bounds__(64) void qkv_fused_kernel(
    const unsigned short* __restrict__ la, const unsigned short* __restrict__ xhat,
    const unsigned short* __restrict__ wlatT, const float* __restrict__ bias_l,
    unsigned short* __restrict__ qb, unsigned short* __restrict__ kb,
    unsigned short* __restrict__ vt)
{
    int lane = threadIdx.x;
    int lr = lane & 15, lg = lane >> 4;

    const unsigned short* A;
    const unsigned short* Bt;
    long m0, n0;
    int M, rpb, joff, qcols;
    bool isLat;
    int T = xcd_swz(blockIdx.x, 1608);
    if (T < 552) {
        int bm = T % 23, bn = T / 23;
        A = la; Bt = wlatT;
        m0 = (long)bm * 64; n0 = (long)bn * 64;
        M = MLAT; rpb = NL; joff = F; qcols = 512; isLat = true;
    } else {
        int Ti = T - 552;
        int bm = Ti % 66, bn = Ti / 66;
        A = xhat; Bt = wlatT + WL_LAT;
        m0 = (long)bm * 64; n0 = (long)bn * 64;
        M = MX; rpb = F; joff = 0; qcols = 0; isLat = false;
    }

    const unsigned short* ap = A  + (m0 + lr) * D + lg * 8;
    const unsigned short* bp = Bt + (n0 + lr) * D + lg * 8;
    f32x4 acc[4][4] = {};
    gemm_core(ap, bp, 16L * D, D, acc);

#pragma unroll
    for (int mm = 0; mm < 4; ++mm) {
        long ar0 = m0 + mm * 16 + lg * 4;
        if (ar0 >= M) continue;
#pragma unroll
        for (int nn = 0; nn < 4; ++nn) {
            long col = n0 + nn * 16 + lr;
            float bcol = isLat ? bias_l[col] : bias_l[1536 + col];
            f32x4 v = acc[mm][nn];
#pragma unroll
            for (int r = 0; r < 4; ++r) v[r] += bcol;
            if (col < qcols) {
#pragma unroll
                for (int r = 0; r < 4; ++r) {
                    long ar = ar0 + r;
                    if (ar < M) {
                        int bb = ar >= NL;
                        long i = ar - (bb ? NL : 0);
                        qb[((long)bb * NL_PAD + i) * INNER + col] = f2bf(v[r] * 0.125f);
                    }
                }
            } else {
                int c = (int)col - qcols;    // 0..1023
                if (c < 512) {               // K-part
#pragma unroll
                    for (int r = 0; r < 4; ++r) {
                        long ar = ar0 + r;
                        if (ar < M) {
                            int bb = ar >= rpb;
                            long i = ar - (bb ? rpb : 0);
                            kb[((long)bb * FN_PAD + joff + i) * INNER + c] = f2bf(v[r]);
                        }
                    }
                } else {                     // V-part (transposed store)
                    int d = c - 512;
                    int bb0 = ar0 >= rpb;
                    int bb3 = (ar0 + 3) >= rpb;
                    long i0 = ar0 - (bb0 ? rpb : 0);
                    long j0 = joff + i0;
                    if ((ar0 + 3 < M) && (bb0 == bb3) && ((j0 & 3) == 0)) {
                        ushort4 pk;
                        pk.x = f2bf(v[0]); pk.y = f2bf(v[1]);
                        pk.z = f2bf(v[2]); pk.w = f2bf(v[3]);
                        *(ushort4*)(vt + ((long)bb0 * INNER + d) * FN_PAD + j0) = pk;
                    } else {
#pragma unroll
                        for (int r = 0; r < 4; ++r) {
                            long ar = ar0 + r;
                            if (ar < M) {
                                int bb = ar >= rpb;
                                long i = ar - (bb ? rpb : 0);
                                vt[((long)bb * INNER + d) * FN_PAD + joff + i] = f2bf(v[r]);
                            }
                        }
                    }
                }
            }
        }
    }
}

// ---------- split-K GEMM, 1-wave blocks, flat grid + XCD chunking ------------
#define MODE_RESA  0   // f32 unsafeAtomicAdd into C[ar*ldc+col]
#define MODE_GELU  1   // bf16 C[ar*ldc+col] = gelu(v + bias[col])

__global__ __launch_bounds__(64) void gemm_split_kernel(
    const unsigned short* __restrict__ A, const unsigned short* __restrict__ Bt,
    void* __restrict__ C, const float* __restrict__ bias,
    int M, int K, int Kc, int mode, int ldc, int bmN, int bnN)
{
    int lane = threadIdx.x;
    int lr = lane & 15, lg = lane >> 4;
    int u = xcd_swz(blockIdx.x, gridDim.x);
    int bm = u % bmN;
    int t2 = u / bmN;
    int bn = t2 % bnN;
    int kz = t2 / bnN;
    long m0 = (long)bm * 64;
    long n0 = (long)bn * 64;
    int k0 = kz * Kc;

    const unsigned short* ap = A  + (m0 + lr) * K + k0 + lg * 8;
    const unsigned short* bp = Bt + (n0 + lr) * K + k0 + lg * 8;
    f32x4 acc[4][4] = {};
    gemm_core(ap, bp, 16L * K, Kc, acc);

#pragma unroll
    for (int mm = 0; mm < 4; ++mm) {
        long ar0 = m0 + mm * 16 + lg * 4;
        if (ar0 >= M) continue;
#pragma unroll
        for (int nn = 0; nn < 4; ++nn) {
            long col = n0 + nn * 16 + lr;
            f32x4 v = acc[mm][nn];
            if (mode == MODE_RESA) {
                float* p = (float*)C;
#pragma unroll
                for (int r = 0; r < 4; ++r)
                    if (ar0 + r < M)
                        unsafeAtomicAdd(&p[(ar0 + r) * (long)ldc + col], v[r]);
            } else {
                float bcol = bias ? bias[col] : 0.f;
                unsigned short* p = (unsigned short*)C;
#pragma unroll
                for (int r = 0; r < 4; ++r)
                    if (ar0 + r < M) {
                        float val = v[r] + bcol;
                        val = 0.5f * val * (1.0f + erff(val * 0.70710678118654752f));
                        p[(ar0 + r) * (long)ldc + col] = f2bf(val);
                    }
            }
        }
    }
}

// ------------- MFMA flash attention, split-KV, flat grid + XCD chunking ------
__global__ __launch_bounds__(256) void attn_split_kernel(
    const unsigned short* __restrict__ qb, const unsigned short* __restrict__ kb,
    const unsigned short* __restrict__ vt, const int* __restrict__ split,
    float* __restrict__ po, float* __restrict__ pml, int skv)
{
    int u = xcd_swz(blockIdx.x, gridDim.x);
    int q64  = u % 12;
    int bh   = (u / 12) % NBH;
    int sidx = u / (12 * NBH);
    int b  = bh >> 3;
    int h  = bh & 7;
    int w  = threadIdx.x >> 6;
    int lane = threadIdx.x & 63;
    int q0 = q64 * 64 + w * 16;
    if (q0 >= NL) return;

    __shared__ unsigned short p_lds[4][16 * 64];   // 2KB per wave, XOR-swizzled
    unsigned short* pl = p_lds[w];

    int lr = lane & 15;
    int lg = lane >> 4;

    bf16x8 qa0, qa1;
    {
        const unsigned short* qrow = qb + ((long)b * NL_PAD + q0 + lr) * INNER + h * 64;
        qa0 = *(const bf16x8*)(qrow + lg * 8);
        qa1 = *(const bf16x8*)(qrow + 32 + lg * 8);
    }

    f32x4 oacc[4] = {{0,0,0,0},{0,0,0,0},{0,0,0,0},{0,0,0,0}};
    float m[4]    = {-1e30f, -1e30f, -1e30f, -1e30f};
    float lsum[4] = {0.f, 0.f, 0.f, 0.f};

    int sp = split[b];
    if (sp < 0) sp = 0;
    if (sp > F) sp = F;
    int ntx = (sp + 63) >> 6;
    int ntot = ntx + 12;
    int t0 = (ntot * sidx) / skv;
    int t1 = (ntot * (sidx + 1)) / skv;

    for (int t = t0; t < t1; ++t) {
        int j0, limit;
        if (t < ntx) { j0 = t * 64;             limit = sp; }
        else         { j0 = F + (t - ntx) * 64; limit = FN; }

        f32x4 s[4] = {{0,0,0,0},{0,0,0,0},{0,0,0,0},{0,0,0,0}};
        const unsigned short* kbase =
            kb + ((long)b * FN_PAD + j0 + lr) * INNER + h * 64 + lg * 8;
#pragma unroll
        for (int st = 0; st < 4; ++st) {
            bf16x8 kf0 = *(const bf16x8*)(kbase + (long)st * 16 * INNER);
            bf16x8 kf1 = *(const bf16x8*)(kbase + (long)st * 16 * INNER + 32);
            s[st] = __builtin_amdgcn_mfma_f32_16x16x32_bf16(qa0, kf0, s[st], 0, 0, 0);
            s[st] = __builtin_amdgcn_mfma_f32_16x16x32_bf16(qa1, kf1, s[st], 0, 0, 0);
        }

        if (j0 + 64 > limit) {
#pragma unroll
            for (int st = 0; st < 4; ++st) {
                bool valid = (j0 + st * 16 + lr) < limit;
#pragma unroll
                for (int r = 0; r < 4; ++r)
                    s[st][r] = valid ? s[st][r] : -1e30f;
            }
        }

        float tm[4];
#pragma unroll
        for (int r = 0; r < 4; ++r)
            tm[r] = fmaxf(fmaxf(s[0][r], s[1][r]), fmaxf(s[2][r], s[3][r]));
#pragma unroll
        for (int off = 1; off < 16; off <<= 1) {
#pragma unroll
            for (int r = 0; r < 4; ++r)
                tm[r] = fmaxf(tm[r], __shfl_xor(tm[r], off));
        }
        float cr[4];
#pragma unroll
        for (int r = 0; r < 4; ++r) {
            float mn = fmaxf(m[r], tm[r]);
            cr[r] = __expf(m[r] - mn);
            m[r]  = mn;
        }
#pragma unroll
        for (int st = 0; st < 4; ++st)
#pragma unroll
            for (int r = 0; r < 4; ++r)
                s[st][r] = __expf(s[st][r] - m[r]);
        float ts[4];
#pragma unroll
        for (int r = 0; r < 4; ++r)
            ts[r] = (s[0][r] + s[1][r]) + (s[2][r] + s[3][r]);
#pragma unroll
        for (int off = 1; off < 16; off <<= 1) {
#pragma unroll
            for (int r = 0; r < 4; ++r)
                ts[r] += __shfl_xor(ts[r], off);
        }
#pragma unroll
        for (int r = 0; r < 4; ++r)
            lsum[r] = lsum[r] * cr[r] + ts[r];
#pragma unroll
        for (int nst = 0; nst < 4; ++nst)
#pragma unroll
            for (int r = 0; r < 4; ++r)
                oacc[nst][r] *= cr[r];

#pragma unroll
        for (int st = 0; st < 4; ++st)
#pragma unroll
            for (int r = 0; r < 4; ++r) {
                int row  = lg * 4 + r;
                int col  = st * 16 + lr;
                int byte = (row * 128 + col * 2) ^ ((row & 7) << 4);
                *(unsigned short*)((char*)pl + byte) = f2bf(s[st][r]);
            }

#pragma unroll
        for (int kk = 0; kk < 2; ++kk) {
            int row  = lr;
            int byte = (row * 128 + kk * 64 + lg * 16) ^ ((row & 7) << 4);
            bf16x8 pa = *(const bf16x8*)((char*)pl + byte);
#pragma unroll
            for (int nst = 0; nst < 4; ++nst) {
                const unsigned short* vp =
                    vt + ((long)bh * DH + nst * 16 + lr) * FN_PAD + j0 + kk * 32 + lg * 8;
                bf16x8 vf = *(const bf16x8*)vp;
                oacc[nst] = __builtin_amdgcn_mfma_f32_16x16x32_bf16(pa, vf, oacc[nst], 0, 0, 0);
            }
        }
    }

    long base = ((long)sidx * NBH + bh) * NL_PAD;
#pragma unroll
    for (int nst = 0; nst < 4; ++nst)
#pragma unroll
        for (int r = 0; r < 4; ++r) {
            int row = q0 + lg * 4 + r;
            if (row < NL)
                po[(base + row) * DH + nst * 16 + lr] = oacc[nst][r];
        }
    if (lr == 0) {
#pragma unroll
        for (int r = 0; r < 4; ++r) {
            int row = q0 + lg * 4 + r;
            if (row < NL) {
                pml[(base + row) * 2 + 0] = m[r];
                pml[(base + row) * 2 + 1] = lsum[r];
            }
        }
    }
}

// -------- combine skv partials -> ob bf16 (one wave per (b,h,i) row) --------
__global__ __launch_bounds__(256) void attn_combine_kernel(
    const float* __restrict__ po, const float* __restrict__ pml,
    unsigned short* __restrict__ o, int skv)
{
    int row = blockIdx.x * 4 + (threadIdx.x >> 6);
    if (row >= NBH * NL) return;
    int lane = threadIdx.x & 63;
    int bh = row / NL;
    int i  = row - bh * NL;
    int b = bh >> 3, h = bh & 7;

    float m = -1e30f, l = 0.0f, acc = 0.0f;
    for (int s = 0; s < skv; ++s) {
        long base = ((long)s * NBH + bh) * NL_PAD + i;
        float ms = pml[base * 2 + 0];
        float ls = pml[base * 2 + 1];
        float os = po[base * DH + lane];
        float mn = fmaxf(m, ms);
        float c1 = __expf(m - mn);
        float c2 = __expf(ms - mn);
        acc = acc * c1 + os * c2;
        l   = l * c1 + ls * c2;
        m   = mn;
    }
    o[((long)b * NL + i) * INNER + h * 64 + lane] = f2bf(acc / l);
}

// ------------------------------- host side ----------------------------------
extern "C" void kernel_launch(void* const* d_in, const int* in_sizes, int n_in,
                              void* d_out, int out_size, void* d_ws, size_t ws_size,
                              hipStream_t stream)
{
    const float* x        = (const float*)d_in[0];
    const int*   split    = (const int*)d_in[1];
    const float* latents  = (const float*)d_in[2];
    const float* sp_emb   = (const float*)d_in[3];
    const float* fr_emb   = (const float*)d_in[4];
    const float* nm_g     = (const float*)d_in[5];
    const float* nm_b     = (const float*)d_in[6];
    const float* nl_g     = (const float*)d_in[7];
    const float* nl_b     = (const float*)d_in[8];
    const float* wq       = (const float*)d_in[9];
    const float* wkv      = (const float*)d_in[10];
    const float* wo       = (const float*)d_in[11];
    const float* ffn_g    = (const float*)d_in[12];
    const float* ffn_b    = (const float*)d_in[13];
    const float* ffw1     = (const float*)d_in[14];
    const float* ffw2     = (const float*)d_in[15];
    const float* final_g  = (const float*)d_in[16];
    const float* final_b  = (const float*)d_in[17];
    float* out = (float*)d_out;

    // ---- cursor-based workspace layout ----
    char* cur = (char*)d_ws;
    auto alloc = [&](size_t bytes) {
        void* p = (void*)cur;
        cur += (bytes + 255) & ~(size_t)255;
        return p;
    };

    unsigned short* xhat = (unsigned short*)alloc((long)MX * D * 2);
    float* lat  = (float*)alloc((long)B * NL * D * 4);
    unsigned short* la  = (unsigned short*)alloc((long)MLAT_PAD * D * 2);
    unsigned short* fa  = (unsigned short*)alloc((long)MLAT_PAD * D * 2);
    unsigned short* h1b = (unsigned short*)alloc((long)MLAT_PAD * 4 * D * 2);
    unsigned short* ob  = (unsigned short*)alloc((long)MLAT_PAD * INNER * 2);
    unsigned short* qb  = (unsigned short*)alloc((long)B * NL_PAD * INNER * 2);
    unsigned short* kb  = (unsigned short*)alloc((long)B * FN_PAD * INNER * 2);
    unsigned short* vt  = (unsigned short*)alloc((long)B * FN_PAD * INNER * 2);
    float* bias = (float*)alloc((long)DEPTH * NBIAS * 4);
    float* pml  = (float*)alloc((long)SKVMAX * NBH * NL_PAD * 2 * 4);

    size_t fixed = (size_t)(cur - (char*)d_ws);
    const size_t po8 = ((size_t)8 * NBH * NL_PAD * DH * 4 + 255) & ~(size_t)255;
    const size_t po4 = ((size_t)4 * NBH * NL_PAD * DH * 4 + 255) & ~(size_t)255;
    const size_t wb6 = ((size_t)6 * WL_SZ * 2 + 255) & ~(size_t)255;
    const size_t wb1 = ((size_t)WL_SZ * 2 + 255) & ~(size_t)255;
    const size_t margin = 4096;

    int skv;
    bool hoist_w;
    if (fixed + po8 + wb6 + margin <= ws_size)      { skv = 8; hoist_w = true;  }
    else if (fixed + po4 + wb6 + margin <= ws_size) { skv = 4; hoist_w = true;  }
    else if (fixed + po8 + wb1 + margin <= ws_size) { skv = 8; hoist_w = false; }
    else                                            { skv = 4; hoist_w = false; }

    float* po = (float*)alloc(skv == 8 ? po8 : po4);
    unsigned short* wbuf = (unsigned short*)alloc(hoist_w ? wb6 : wb1);

    // zero bias accumulator (graph-capture-safe), then split-K GEMV with atomics
    hipMemsetAsync(bias, 0, (size_t)DEPTH * NBIAS * 4, stream);

    emb_ln_kernel<<<MX, 256, 0, stream>>>(x, sp_emb, fr_emb, xhat);
    lat_init_kernel<<<B * NL, 256, 0, stream>>>(latents, lat);
    bias_kernel<<<dim3(NBIAS / 256, 8, 6), 256, 0, stream>>>(
        wq, wkv, ffw1, nl_b, nm_b, ffn_b, bias);

    if (hoist_w)
        wt_conv_all_kernel<<<dim3(2816, 6), 256, 0, stream>>>(
            wq, wkv, wo, ffw1, ffw2, nl_g, nm_g, ffn_g, wbuf, WL_SZ, 0);

    for (int l = 0; l < DEPTH; ++l) {
        unsigned short* wl = wbuf + (hoist_w ? (long)l * WL_SZ : 0);
        if (!hoist_w)
            wt_conv_all_kernel<<<dim3(2816, 1), 256, 0, stream>>>(
                wq, wkv, wo, ffw1, ffw2, nl_g, nm_g, ffn_g, wbuf, 0, l);

        unsigned short* wlatT = wl;
        unsigned short* woT   = wl + WL_LAT + WL_KVX;
        unsigned short* f1T   = wl + WL_LAT + WL_KVX + WL_WO;
        unsigned short* f2T   = wl + WL_LAT + WL_KVX + WL_WO + WL_F1;
        const float* bias_l = bias + (long)l * NBIAS;

        // la = plain LN(lat)
        rownorm_plain_kernel<<<MLAT, 256, 0, stream>>>(lat, la);

        // fused q/kv(lat) + kv(x): 1608 one-wave blocks, XCD-chunked
        qkv_fused_kernel<<<1608, 64, 0, stream>>>(la, xhat, wlatT, bias_l, qb, kb, vt);

        // attention: split-KV partials (flat grid, XCD-chunked) + combine
        attn_split_kernel<<<12 * NBH * skv, 256, 0, stream>>>(
            qb, kb, vt, split, po, pml, skv);
        attn_combine_kernel<<<(NBH * NL + 3) / 4, 256, 0, stream>>>(po, pml, ob, skv);

        // lat += ob @ wo   (split-K = 4)
        gemm_split_kernel<<<23 * 16 * 4, 64, 0, stream>>>(
            ob, woT, lat, nullptr, MLAT, INNER, 128, MODE_RESA, D, 23, 16);

        // FFN: fa = plain LN(lat); h1 = gelu(fa@f1T + bias); lat += h1@f2T
        rownorm_plain_kernel<<<MLAT, 256, 0, stream>>>(lat, fa);
        gemm_split_kernel<<<23 * 64, 64, 0, stream>>>(
            fa, f1T, h1b, bias_l + 2560, MLAT, D, D, MODE_GELU, 4 * D, 23, 64);
        gemm_split_kernel<<<23 * 16 * 8, 64, 0, stream>>>(
            h1b, f2T, lat, nullptr, MLAT, 4 * D, 512, MODE_RESA, D, 23, 16);
    }

    final_ln_kernel<<<MLAT, 256, 0, stream>>>(lat, final_g, final_b, out);
}